// Round 9
// baseline (60.411 us; speedup 1.0000x reference)
//
#include <hip/hip_runtime.h>
#include <hip/hip_fp16.h>

// Problem constants (fixed by the reference)
#define S_N 32
#define O_N 64
#define A_N 8
#define R_N 8
#define B_N 1024
#define T_N 128

// Workspace layout (float-index offsets):
//  [0, 4096)      TH : packed fp16 transitions (16 KB), as uint4 entries
//                 entry[(a*4+q)*32 + sl] holds rows 8q..8q+7 of column sl
//  [4096, 6144)   OT[o][s]     = P(o|s)
//  [6144, 8192)   RA[r*8+a][s] = P(r|s)*P(a|s)
//  [8192, 8448)   RT[r][s]     = P(r|s)
//  [8448, 8480)   PI[s]
#define OT_OFF   4096
#define RA_OFF   6144
#define RT_OFF   8192
#define PI_OFF   8448

// LDS emission block (floats) — contiguous image of ws[4096..8480)
#define L_OT 0
#define L_RA 2048
#define L_RT 4096
#define L_PI 4352
#define L_N  4384

__global__ __launch_bounds__(256) void tam_prep(
    const float* __restrict__ params_s,
    const float* __restrict__ params_s_sa,
    const float* __restrict__ params_o_s,
    const float* __restrict__ params_r_s,
    const float* __restrict__ params_a_s,
    float* __restrict__ ws)
{
    const int tid = threadIdx.x;
    if (blockIdx.x == 0) {
        // Transitions: 256 threads, one (s,a) row softmax each; scatter fp16.
        const int s = tid >> 3, a = tid & 7;
        const float* row = params_s_sa + (s * A_N + a) * S_N;
        float p[32];
        #pragma unroll
        for (int i = 0; i < 8; ++i) {
            float4 v = reinterpret_cast<const float4*>(row)[i];
            p[4*i]=v.x; p[4*i+1]=v.y; p[4*i+2]=v.z; p[4*i+3]=v.w;
        }
        float mx = p[0];
        #pragma unroll
        for (int i = 1; i < 32; ++i) mx = fmaxf(mx, p[i]);
        float sum = 0.f;
        #pragma unroll
        for (int i = 0; i < 32; ++i) { p[i] = __expf(p[i] - mx); sum += p[i]; }
        const float inv = 1.0f / sum;
        // half index: ((a*4 + (s>>3))*32 + sl)*8 + (s&7)
        __half* wsh = reinterpret_cast<__half*>(ws);
        __half* base = wsh + (size_t)((a * 4 + (s >> 3)) * 32) * 8 + (s & 7);
        #pragma unroll
        for (int sl = 0; sl < 32; ++sl) base[sl * 8] = __float2half_rn(p[sl] * inv);
    } else {
        __shared__ float sRT[256], sAT[256];
        if (tid < 32) {
            // observation emission: softmax over O (64) per state; OT[o][s]
            const int s = tid;
            const float* row = params_o_s + s * O_N;
            float p[64];
            #pragma unroll
            for (int i = 0; i < 16; ++i) {
                float4 v = reinterpret_cast<const float4*>(row)[i];
                p[4*i]=v.x; p[4*i+1]=v.y; p[4*i+2]=v.z; p[4*i+3]=v.w;
            }
            float mx = p[0];
            #pragma unroll
            for (int i = 1; i < 64; ++i) mx = fmaxf(mx, p[i]);
            float sum = 0.f;
            #pragma unroll
            for (int i = 0; i < 64; ++i) { p[i] = __expf(p[i] - mx); sum += p[i]; }
            const float inv = 1.0f / sum;
            #pragma unroll
            for (int o = 0; o < 64; ++o) ws[OT_OFF + o * 32 + s] = p[o] * inv;
        } else if (tid < 64) {
            // reward emission: RT[r][s]
            const int s = tid - 32;
            const float* row = params_r_s + s * R_N;
            float p[8];
            #pragma unroll
            for (int i = 0; i < 2; ++i) {
                float4 v = reinterpret_cast<const float4*>(row)[i];
                p[4*i]=v.x; p[4*i+1]=v.y; p[4*i+2]=v.z; p[4*i+3]=v.w;
            }
            float mx = p[0];
            #pragma unroll
            for (int i = 1; i < 8; ++i) mx = fmaxf(mx, p[i]);
            float sum = 0.f;
            #pragma unroll
            for (int i = 0; i < 8; ++i) { p[i] = __expf(p[i] - mx); sum += p[i]; }
            const float inv = 1.0f / sum;
            #pragma unroll
            for (int r = 0; r < 8; ++r) {
                const float v = p[r] * inv;
                ws[RT_OFF + r * 32 + s] = v;
                sRT[r * 32 + s] = v;
            }
        } else if (tid < 96) {
            // action prior: AT[a][s] (LDS only, feeds RA)
            const int s = tid - 64;
            const float* row = params_a_s + s * A_N;
            float p[8];
            #pragma unroll
            for (int i = 0; i < 2; ++i) {
                float4 v = reinterpret_cast<const float4*>(row)[i];
                p[4*i]=v.x; p[4*i+1]=v.y; p[4*i+2]=v.z; p[4*i+3]=v.w;
            }
            float mx = p[0];
            #pragma unroll
            for (int i = 1; i < 8; ++i) mx = fmaxf(mx, p[i]);
            float sum = 0.f;
            #pragma unroll
            for (int i = 0; i < 8; ++i) { p[i] = __expf(p[i] - mx); sum += p[i]; }
            const float inv = 1.0f / sum;
            #pragma unroll
            for (int a = 0; a < 8; ++a) sAT[a * 32 + s] = p[a] * inv;
        } else if (tid < 128) {
            // pi = softmax(params_s): redundant compute, write own element
            const int s = tid - 96;
            float p[32];
            #pragma unroll
            for (int i = 0; i < 8; ++i) {
                float4 v = reinterpret_cast<const float4*>(params_s)[i];
                p[4*i]=v.x; p[4*i+1]=v.y; p[4*i+2]=v.z; p[4*i+3]=v.w;
            }
            float mx = p[0];
            #pragma unroll
            for (int i = 1; i < 32; ++i) mx = fmaxf(mx, p[i]);
            float sum = 0.f;
            #pragma unroll
            for (int i = 0; i < 32; ++i) { p[i] = __expf(p[i] - mx); sum += p[i]; }
            ws[PI_OFF + s] = p[s] / sum;
        }
        __syncthreads();
        // RA[r*8+a][s] = RT[r][s] * AT[a][s]
        #pragma unroll 1
        for (int i = tid; i < 2048; i += 256) {
            const int sl = i & 31, ra = i >> 5;
            ws[RA_OFF + i] = sRT[(ra >> 3) * 32 + sl] * sAT[(ra & 7) * 32 + sl];
        }
    }
}

#define RLI(v, l) __builtin_amdgcn_readlane((v), (l))
// ds_swizzle broadcast: offset (BitMode) = (xor<<10)|(or<<5)|(and); and=0,xor=0,
// or=k -> every lane of each 32-lane group reads that group's lane k. VGPR->VGPR,
// no SGPR writes -> no VALU-write-SGPR/VALU-read-SGPR hazards in the hot loop.
#define SWZ(v, off) __builtin_amdgcn_ds_swizzle((v), (off))
#define SWF(v, k)   __int_as_float(SWZ(__float_as_int(v), (k) << 5))

static __device__ __forceinline__ __half2 u2h(unsigned u) {
    union { unsigned u; __half2 h; } c; c.u = u; return c.h;
}

// Load action A_'s 32x32 fp16 transition column sl: 4 x ds_read_b128,
// address-indexed (NO branches). TH[k] = half2(row 2k, row 2k+1).
#define LOADTH(TH, A_) {                                                     \
    const uint4* p_ = sTH + ((A_) << 7) + sl;                                \
    const uint4 q0_ = p_[0], q1_ = p_[32], q2_ = p_[64], q3_ = p_[96];       \
    TH[0]=q0_.x;  TH[1]=q0_.y;  TH[2]=q0_.z;  TH[3]=q0_.w;                   \
    TH[4]=q1_.x;  TH[5]=q1_.y;  TH[6]=q1_.z;  TH[7]=q1_.w;                   \
    TH[8]=q2_.x;  TH[9]=q2_.y;  TH[10]=q2_.z; TH[11]=q2_.w;                  \
    TH[12]=q3_.x; TH[13]=q3_.y; TH[14]=q3_.z; TH[15]=q3_.w; }

// Emission factors for the step encoded in the low 16 bits of PKW (from LDS)
#define LOADE(EO, ERA, PKW) {                                                \
    const unsigned pk_ = (PKW);                                              \
    EO  = sE[(int)(pk_ & 63u) * 32 + sl];                                    \
    ERA = sE[eBase + (int)((pk_ >> 6) & 7u) * eMulR                          \
                   + (int)((pk_ >> 9) & 7u) * eMulA + sl]; }

// Load a full step-pair (2 steps) from the packed word PKW into buffers
#define LOADPAIR(EO0, ERA0, TH0, EO1, ERA1, TH1, PKW) {                      \
    const unsigned pw_ = (PKW);                                              \
    LOADE(EO0, ERA0, pw_ & 0xffffu);                                         \
    LOADE(EO1, ERA1, pw_ >> 16);                                             \
    LOADTH(TH0, (int)((pw_ >> 9) & 7u));                                     \
    LOADTH(TH1, (int)((pw_ >> 25) & 7u)); }

// Keep-alive fence: forces the prefetched values to be resident in VGPRs at
// this point — the scheduler cannot sink the ds_reads past it (rule 17/18).
#define KA4(a, b, c, d) asm volatile("" : "+v"(a), "+v"(b), "+v"(c), "+v"(d));
#define KEEPP(TH0, TH1, EO0, ERA0, EO1, ERA1) {                              \
    KA4(TH0[0],TH0[1],TH0[2],TH0[3])   KA4(TH0[4],TH0[5],TH0[6],TH0[7])      \
    KA4(TH0[8],TH0[9],TH0[10],TH0[11]) KA4(TH0[12],TH0[13],TH0[14],TH0[15])  \
    KA4(TH1[0],TH1[1],TH1[2],TH1[3])   KA4(TH1[4],TH1[5],TH1[6],TH1[7])      \
    KA4(TH1[8],TH1[9],TH1[10],TH1[11]) KA4(TH1[12],TH1[13],TH1[14],TH1[15])  \
    KA4(EO0, ERA0, EO1, ERA1) }

// One HMM step: w = u .* e ; u' = T_a^T w. Broadcasts via ds_swizzle
// (VGPR->VGPR), 32 mixed-precision fmas on 4 accumulator chains.
#define STEP(EO, ERA, TH) {                                                  \
    const float wv = u * (EO) * (ERA);                                       \
    const float w0 =SWF(wv,0),  w1 =SWF(wv,1),  w2 =SWF(wv,2),  w3 =SWF(wv,3),  \
                w4 =SWF(wv,4),  w5 =SWF(wv,5),  w6 =SWF(wv,6),  w7 =SWF(wv,7),  \
                w8 =SWF(wv,8),  w9 =SWF(wv,9),  w10=SWF(wv,10), w11=SWF(wv,11), \
                w12=SWF(wv,12), w13=SWF(wv,13), w14=SWF(wv,14), w15=SWF(wv,15), \
                w16=SWF(wv,16), w17=SWF(wv,17), w18=SWF(wv,18), w19=SWF(wv,19), \
                w20=SWF(wv,20), w21=SWF(wv,21), w22=SWF(wv,22), w23=SWF(wv,23), \
                w24=SWF(wv,24), w25=SWF(wv,25), w26=SWF(wv,26), w27=SWF(wv,27), \
                w28=SWF(wv,28), w29=SWF(wv,29), w30=SWF(wv,30), w31=SWF(wv,31); \
    float c0 = 0.f, c1 = 0.f, c2 = 0.f, c3 = 0.f;                            \
    c0=fmaf(w0, __low2float(u2h(TH[0])), c0); c1=fmaf(w1, __high2float(u2h(TH[0])), c1); \
    c2=fmaf(w2, __low2float(u2h(TH[1])), c2); c3=fmaf(w3, __high2float(u2h(TH[1])), c3); \
    c0=fmaf(w4, __low2float(u2h(TH[2])), c0); c1=fmaf(w5, __high2float(u2h(TH[2])), c1); \
    c2=fmaf(w6, __low2float(u2h(TH[3])), c2); c3=fmaf(w7, __high2float(u2h(TH[3])), c3); \
    c0=fmaf(w8, __low2float(u2h(TH[4])), c0); c1=fmaf(w9, __high2float(u2h(TH[4])), c1); \
    c2=fmaf(w10,__low2float(u2h(TH[5])), c2); c3=fmaf(w11,__high2float(u2h(TH[5])), c3); \
    c0=fmaf(w12,__low2float(u2h(TH[6])), c0); c1=fmaf(w13,__high2float(u2h(TH[6])), c1); \
    c2=fmaf(w14,__low2float(u2h(TH[7])), c2); c3=fmaf(w15,__high2float(u2h(TH[7])), c3); \
    c0=fmaf(w16,__low2float(u2h(TH[8])), c0); c1=fmaf(w17,__high2float(u2h(TH[8])), c1); \
    c2=fmaf(w18,__low2float(u2h(TH[9])), c2); c3=fmaf(w19,__high2float(u2h(TH[9])), c3); \
    c0=fmaf(w20,__low2float(u2h(TH[10])),c0); c1=fmaf(w21,__high2float(u2h(TH[10])),c1); \
    c2=fmaf(w22,__low2float(u2h(TH[11])),c2); c3=fmaf(w23,__high2float(u2h(TH[11])),c3); \
    c0=fmaf(w24,__low2float(u2h(TH[12])),c0); c1=fmaf(w25,__high2float(u2h(TH[12])),c1); \
    c2=fmaf(w26,__low2float(u2h(TH[13])),c2); c3=fmaf(w27,__high2float(u2h(TH[13])),c3); \
    c0=fmaf(w28,__low2float(u2h(TH[14])),c0); c1=fmaf(w29,__high2float(u2h(TH[14])),c1); \
    c2=fmaf(w30,__low2float(u2h(TH[15])),c2); c3=fmaf(w31,__high2float(u2h(TH[15])),c3); \
    u = (c0 + c1) + (c2 + c3); }

// exact power-of-two rescale; magnitude proxy via swizzle-broadcast of lane 0
#define RESCALE() {                                                          \
    const int ub = SWZ(__float_as_int(u), 0);                                \
    const int kb = (ub >> 23) & 255;                                         \
    u *= __int_as_float((254 - kb) << 23);                                   \
    ksum += kb - 127; }

// 4 waves per block, ONE episode per wave, shared LDS tables. Pair-ahead
// double-buffered pipeline with keep-alive fences pinning the prefetch.
__global__ __launch_bounds__(256) void tam_main(
    const float* __restrict__ regime,
    const int*   __restrict__ obs,
    const int*   __restrict__ rewards,
    const int*   __restrict__ dones_i,   // float32 0/1 read as int bits
    const int*   __restrict__ actions,
    const float* __restrict__ ws,
    float* __restrict__ out)
{
    __shared__ uint4 sTH[1024];          // 16 KB packed fp16 transitions
    __shared__ float sE[L_N];            // 17.1 KB emission block
    const int tid  = threadIdx.x;
    const int lane = tid & 63;
    const int wid  = tid >> 6;
    const int sl   = lane & 31;
    const int b    = blockIdx.x * 4 + wid;

    // stage T (16 KB) and emissions (17.1 KB) into LDS — 256 threads
    {
        const uint4* gt = reinterpret_cast<const uint4*>(ws);
        #pragma unroll
        for (int i = 0; i < 4; ++i) sTH[tid + i * 256] = gt[tid + i * 256];
        const float4* ge = reinterpret_cast<const float4*>(ws + OT_OFF);
        float4* s4 = reinterpret_cast<float4*>(sE);
        #pragma unroll 1
        for (int i = tid; i < L_N / 4; i += 256) s4[i] = ge[i];
    }
    __syncthreads();

    // per-lane packed step-pair indices: lane i holds steps 2i (low16), 2i+1 (high16)
    const int t0 = 2 * lane, t1 = 2 * lane + 1;
    const int o0 = obs[t0 * B_N + b],      o1 = obs[t1 * B_N + b];
    const int r0 = rewards[t0 * B_N + b],  r1 = rewards[t1 * B_N + b];
    const int a0 = actions[t0 * B_N + b],  a1 = actions[t1 * B_N + b];
    const int d0 = dones_i[t0 * B_N + b],  d1 = dones_i[t1 * B_N + b];
    const int vpk = (o0 | (r0 << 6) | (a0 << 9)) |
                    ((o1 | (r1 << 6) | (a1 << 9)) << 16);

    // first-done step t* via ballot (per-wave; no done checks in the hot loop)
    const unsigned long long mE = __ballot(d0 != 0);
    const unsigned long long mO = __ballot(d1 != 0);
    const int tE = mE ? 2 * __builtin_ctzll(mE)     : (1 << 30);
    const int tO = mO ? 2 * __builtin_ctzll(mO) + 1 : (1 << 30);
    const int tstar  = tE < tO ? tE : tO;
    const int nsteps = tstar < 128 ? tstar : 128;

    // regime==1 -> action term excluded every step: use RT table (a ignored)
    const bool skipA = (regime[b] == 1.0f);
    const int eBase = skipA ? L_RT : L_RA;
    const int eMulR = skipA ? 32 : 256;
    const int eMulA = skipA ? 0 : 32;

    float u = sE[L_PI + sl];
    int ksum = 0;

    // X/Y pair buffers (all register indices compile-time constant)
    unsigned thX0[16], thX1[16], thY0[16], thY1[16];
    float eoX0, eraX0, eoX1, eraX1, eoY0, eraY0, eoY1, eraY1;

    // prologue: X <- pair 0, Y <- pair 1 (speculative beyond nsteps is safe:
    // readlane lane index wraps mod 64, fields always address valid LDS)
    LOADPAIR(eoX0, eraX0, thX0, eoX1, eraX1, thX1, (unsigned)RLI(vpk, 0));
    LOADPAIR(eoY0, eraY0, thY0, eoY1, eraY1, thY1, (unsigned)RLI(vpk, 1));
    unsigned pkX = (unsigned)RLI(vpk, 2);   // pair index for next X refill
    unsigned pkY = (unsigned)RLI(vpk, 3);

    const int npairs = nsteps >> 1;
    #pragma unroll 1
    for (int i = 0; i + 1 < npairs; i += 2) {
        // pair i from X (loaded >= 2 STEPs ago); fence pins loads + wait here
        KEEPP(thX0, thX1, eoX0, eraX0, eoX1, eraX1);
        STEP(eoX0, eraX0, thX0);
        STEP(eoX1, eraX1, thX1);
        RESCALE();
        LOADPAIR(eoX0, eraX0, thX0, eoX1, eraX1, thX1, pkX);
        pkX = (unsigned)RLI(vpk, i + 4);
        // pair i+1 from Y, refill Y with pair i+3
        KEEPP(thY0, thY1, eoY0, eraY0, eoY1, eraY1);
        STEP(eoY0, eraY0, thY0);
        STEP(eoY1, eraY1, thY1);
        RESCALE();
        LOADPAIR(eoY0, eraY0, thY0, eoY1, eraY1, thY1, pkY);
        pkY = (unsigned)RLI(vpk, i + 5);
    }

    // leftover pair (npairs odd): even-indexed pairs live in X
    if (npairs & 1) {
        STEP(eoX0, eraX0, thX0);
        STEP(eoX1, eraX1, thX1);
        RESCALE();
    }
    // leftover odd step = low half of pair `npairs`: X if npairs even, else Y
    if (nsteps & 1) {
        if (npairs & 1) { STEP(eoY0, eraY0, thY0); }
        else            { STEP(eoX0, eraX0, thX0); }
    }

    // terminal contribution at e = min(t*, 128): OT*RT only (no action term)
    {
        const int e  = nsteps;
        const int oe = obs[e * B_N + b];
        const int re = rewards[e * B_N + b];
        const float eo = sE[L_OT + oe * 32 + sl];
        const float rt = sE[L_RT + re * 32 + sl];
        float t = u * eo * rt;
        t += __shfl_xor(t, 1, 32);
        t += __shfl_xor(t, 2, 32);
        t += __shfl_xor(t, 4, 32);
        t += __shfl_xor(t, 8, 32);
        t += __shfl_xor(t, 16, 32);
        const float result = (float)ksum * 0.69314718055994531f + __logf(t);
        if (lane == 0) out[b] = result;
    }
}

extern "C" void kernel_launch(void* const* d_in, const int* in_sizes, int n_in,
                              void* d_out, int out_size, void* d_ws, size_t ws_size,
                              hipStream_t stream) {
    (void)in_sizes; (void)n_in; (void)out_size; (void)ws_size;
    const float* regime      = (const float*)d_in[0];
    const int*   obs         = (const int*)d_in[1];
    const int*   rewards     = (const int*)d_in[2];
    const int*   dones_i     = (const int*)d_in[3];
    const int*   actions     = (const int*)d_in[4];
    const float* params_s    = (const float*)d_in[5];
    const float* params_s_sa = (const float*)d_in[6];
    const float* params_o_s  = (const float*)d_in[7];
    const float* params_r_s  = (const float*)d_in[8];
    const float* params_a_s  = (const float*)d_in[9];
    float* ws  = (float*)d_ws;
    float* out = (float*)d_out;

    tam_prep<<<2, 256, 0, stream>>>(params_s, params_s_sa, params_o_s,
                                    params_r_s, params_a_s, ws);
    tam_main<<<256, 256, 0, stream>>>(regime, obs, rewards, dones_i, actions, ws, out);
}

// Round 12
// 48.620 us; speedup vs baseline: 1.2425x; 1.2425x over previous
//
#include <hip/hip_runtime.h>

// Problem constants (fixed by the reference)
#define S_N 32
#define O_N 64
#define A_N 8
#define R_N 8
#define B_N 1024
#define T_N 128

// Workspace layout (float-index offsets):
//  [0, 8192)        TF : fp32 transitions as float4 entries
//                   entry[(a*8+q)*32 + sl] holds rows 4q..4q+3 of column sl
//                   (component j = Tr[4q+j][a][sl])
//  [8192, 10240)    OT[o][s]     = P(o|s)
//  [10240, 12288)   RA[r*8+a][s] = P(r|s)*P(a|s)
//  [12288, 12544)   RT[r][s]     = P(r|s)
//  [12544, 12576)   PI[s]
#define OT_OFF   8192
#define RA_OFF   10240
#define RT_OFF   12288
#define PI_OFF   12544

// LDS emission block (floats) — contiguous image of ws[8192..12576)
#define L_OT 0
#define L_RA 2048
#define L_RT 4096
#define L_PI 4352
#define L_N  4384

__global__ __launch_bounds__(256) void tam_prep(
    const float* __restrict__ params_s,
    const float* __restrict__ params_s_sa,
    const float* __restrict__ params_o_s,
    const float* __restrict__ params_r_s,
    const float* __restrict__ params_a_s,
    float* __restrict__ ws)
{
    const int tid = threadIdx.x;
    if (blockIdx.x == 0) {
        // Transitions: 256 threads, one (s,a) row softmax each; fp32 scatter.
        const int s = tid >> 3, a = tid & 7;
        const float* row = params_s_sa + (s * A_N + a) * S_N;
        float p[32];
        #pragma unroll
        for (int i = 0; i < 8; ++i) {
            float4 v = reinterpret_cast<const float4*>(row)[i];
            p[4*i]=v.x; p[4*i+1]=v.y; p[4*i+2]=v.z; p[4*i+3]=v.w;
        }
        float mx = p[0];
        #pragma unroll
        for (int i = 1; i < 32; ++i) mx = fmaxf(mx, p[i]);
        float sum = 0.f;
        #pragma unroll
        for (int i = 0; i < 32; ++i) { p[i] = __expf(p[i] - mx); sum += p[i]; }
        const float inv = 1.0f / sum;
        // float index: ((a*8 + (s>>2))*32 + sl)*4 + (s&3)
        float* base = ws + (size_t)(a * 8 + (s >> 2)) * 128 + (s & 3);
        #pragma unroll
        for (int sl = 0; sl < 32; ++sl) base[sl * 4] = p[sl] * inv;
    } else {
        __shared__ float sRT[256], sAT[256];
        if (tid < 32) {
            // observation emission: softmax over O (64) per state; OT[o][s]
            const int s = tid;
            const float* row = params_o_s + s * O_N;
            float p[64];
            #pragma unroll
            for (int i = 0; i < 16; ++i) {
                float4 v = reinterpret_cast<const float4*>(row)[i];
                p[4*i]=v.x; p[4*i+1]=v.y; p[4*i+2]=v.z; p[4*i+3]=v.w;
            }
            float mx = p[0];
            #pragma unroll
            for (int i = 1; i < 64; ++i) mx = fmaxf(mx, p[i]);
            float sum = 0.f;
            #pragma unroll
            for (int i = 0; i < 64; ++i) { p[i] = __expf(p[i] - mx); sum += p[i]; }
            const float inv = 1.0f / sum;
            #pragma unroll
            for (int o = 0; o < 64; ++o) ws[OT_OFF + o * 32 + s] = p[o] * inv;
        } else if (tid < 64) {
            // reward emission: RT[r][s]
            const int s = tid - 32;
            const float* row = params_r_s + s * R_N;
            float p[8];
            #pragma unroll
            for (int i = 0; i < 2; ++i) {
                float4 v = reinterpret_cast<const float4*>(row)[i];
                p[4*i]=v.x; p[4*i+1]=v.y; p[4*i+2]=v.z; p[4*i+3]=v.w;
            }
            float mx = p[0];
            #pragma unroll
            for (int i = 1; i < 8; ++i) mx = fmaxf(mx, p[i]);
            float sum = 0.f;
            #pragma unroll
            for (int i = 0; i < 8; ++i) { p[i] = __expf(p[i] - mx); sum += p[i]; }
            const float inv = 1.0f / sum;
            #pragma unroll
            for (int r = 0; r < 8; ++r) {
                const float v = p[r] * inv;
                ws[RT_OFF + r * 32 + s] = v;
                sRT[r * 32 + s] = v;
            }
        } else if (tid < 96) {
            // action prior: AT[a][s] (LDS only, feeds RA)
            const int s = tid - 64;
            const float* row = params_a_s + s * A_N;
            float p[8];
            #pragma unroll
            for (int i = 0; i < 2; ++i) {
                float4 v = reinterpret_cast<const float4*>(row)[i];
                p[4*i]=v.x; p[4*i+1]=v.y; p[4*i+2]=v.z; p[4*i+3]=v.w;
            }
            float mx = p[0];
            #pragma unroll
            for (int i = 1; i < 8; ++i) mx = fmaxf(mx, p[i]);
            float sum = 0.f;
            #pragma unroll
            for (int i = 0; i < 8; ++i) { p[i] = __expf(p[i] - mx); sum += p[i]; }
            const float inv = 1.0f / sum;
            #pragma unroll
            for (int a = 0; a < 8; ++a) sAT[a * 32 + s] = p[a] * inv;
        } else if (tid < 128) {
            // pi = softmax(params_s): redundant compute, write own element
            const int s = tid - 96;
            float p[32];
            #pragma unroll
            for (int i = 0; i < 8; ++i) {
                float4 v = reinterpret_cast<const float4*>(params_s)[i];
                p[4*i]=v.x; p[4*i+1]=v.y; p[4*i+2]=v.z; p[4*i+3]=v.w;
            }
            float mx = p[0];
            #pragma unroll
            for (int i = 1; i < 32; ++i) mx = fmaxf(mx, p[i]);
            float sum = 0.f;
            #pragma unroll
            for (int i = 0; i < 32; ++i) { p[i] = __expf(p[i] - mx); sum += p[i]; }
            ws[PI_OFF + s] = p[s] / sum;
        }
        __syncthreads();
        // RA[r*8+a][s] = RT[r][s] * AT[a][s]
        #pragma unroll 1
        for (int i = tid; i < 2048; i += 256) {
            const int sl = i & 31, ra = i >> 5;
            ws[RA_OFF + i] = sRT[(ra >> 3) * 32 + sl] * sAT[(ra & 7) * 32 + sl];
        }
    }
}

#define RLI(v, l) __builtin_amdgcn_readlane((v), (l))
// bf16 pair unpack: sk is wave-uniform (readlane result) -> these become SALU
// ops (scalar pipe, concurrent with VALU) feeding fmas as SGPR operands.
#define BL(k) __int_as_float((int)((unsigned)(k) << 16))
#define BH(k) __int_as_float((int)((k) & 0xffff0000u))

// Load action A_'s 32x32 fp32 transition column sl: 8 x ds_read_b128,
// address-indexed (NO branches). TF[q] = rows 4q..4q+3 of column sl.
#define LOADTF(TF, A_) {                                                     \
    const float4* p_ = sTF + ((A_) << 8) + sl;                               \
    TF[0] = p_[0];   TF[1] = p_[32];  TF[2] = p_[64];  TF[3] = p_[96];       \
    TF[4] = p_[128]; TF[5] = p_[160]; TF[6] = p_[192]; TF[7] = p_[224]; }

// Emission factor product for the step in the low 16 bits of PKW (off the
// u-dependency path — computed at load/prefetch time).
#define LOADE(E, PKW) {                                                      \
    const unsigned pk_ = (PKW);                                              \
    const float eo_  = sE[(int)(pk_ & 63u) * 32 + sl];                       \
    const float era_ = sE[eBase + (int)((pk_ >> 6) & 7u) * eMulR             \
                        + (int)((pk_ >> 9) & 7u) * eMulA + sl];              \
    E = eo_ * era_; }

// One HMM step: w = u*E; round w to bf16 (+0x8000), DPP quad-swap gives the
// neighbor, pack (w[2k],w[2k+1]) as bf16x2 -> only 16 readlane broadcasts;
// SALU unpack; 32 fp32 fmas on 4 accumulator chains against fp32 T.
#define STEP(E, TF) {                                                        \
    const float wv_ = u * (E);                                               \
    const int wvb_ = __float_as_int(wv_) + 0x8000;                           \
    const int wpb_ = __builtin_amdgcn_mov_dpp(wvb_, 0xB1, 0xF, 0xF, true);   \
    const unsigned whi_ = ((unsigned)wvb_ >> 16) | ((unsigned)wpb_ & 0xffff0000u); \
    const int k0 =RLI(whi_,0),  k1 =RLI(whi_,2),  k2 =RLI(whi_,4),  k3 =RLI(whi_,6),  \
              k4 =RLI(whi_,8),  k5 =RLI(whi_,10), k6 =RLI(whi_,12), k7 =RLI(whi_,14), \
              k8 =RLI(whi_,16), k9 =RLI(whi_,18), k10=RLI(whi_,20), k11=RLI(whi_,22), \
              k12=RLI(whi_,24), k13=RLI(whi_,26), k14=RLI(whi_,28), k15=RLI(whi_,30); \
    float c0 = 0.f, c1 = 0.f, c2 = 0.f, c3 = 0.f;                            \
    c0=fmaf(BL(k0),  TF[0].x, c0); c1=fmaf(BH(k0),  TF[0].y, c1);            \
    c2=fmaf(BL(k1),  TF[0].z, c2); c3=fmaf(BH(k1),  TF[0].w, c3);            \
    c0=fmaf(BL(k2),  TF[1].x, c0); c1=fmaf(BH(k2),  TF[1].y, c1);            \
    c2=fmaf(BL(k3),  TF[1].z, c2); c3=fmaf(BH(k3),  TF[1].w, c3);            \
    c0=fmaf(BL(k4),  TF[2].x, c0); c1=fmaf(BH(k4),  TF[2].y, c1);            \
    c2=fmaf(BL(k5),  TF[2].z, c2); c3=fmaf(BH(k5),  TF[2].w, c3);            \
    c0=fmaf(BL(k6),  TF[3].x, c0); c1=fmaf(BH(k6),  TF[3].y, c1);            \
    c2=fmaf(BL(k7),  TF[3].z, c2); c3=fmaf(BH(k7),  TF[3].w, c3);            \
    c0=fmaf(BL(k8),  TF[4].x, c0); c1=fmaf(BH(k8),  TF[4].y, c1);            \
    c2=fmaf(BL(k9),  TF[4].z, c2); c3=fmaf(BH(k9),  TF[4].w, c3);            \
    c0=fmaf(BL(k10), TF[5].x, c0); c1=fmaf(BH(k10), TF[5].y, c1);            \
    c2=fmaf(BL(k11), TF[5].z, c2); c3=fmaf(BH(k11), TF[5].w, c3);            \
    c0=fmaf(BL(k12), TF[6].x, c0); c1=fmaf(BH(k12), TF[6].y, c1);            \
    c2=fmaf(BL(k13), TF[6].z, c2); c3=fmaf(BH(k13), TF[6].w, c3);            \
    c0=fmaf(BL(k14), TF[7].x, c0); c1=fmaf(BH(k14), TF[7].y, c1);            \
    c2=fmaf(BL(k15), TF[7].z, c2); c3=fmaf(BH(k15), TF[7].w, c3);            \
    u = (c0 + c1) + (c2 + c3); }

// exact power-of-two rescale every 2 steps (u stays fp32; bf16 has fp32's
// exponent range so the lane-0 proxy is safe — the r3..r8 validated scheme)
#define RESCALE() {                                                          \
    const int ub = RLI(__float_as_int(u), 0);                                \
    const int kb = (ub >> 23) & 255;                                         \
    u *= __int_as_float((254 - kb) << 23);                                   \
    ksum += kb - 127; }

// 4 waves per block, ONE episode per wave, shared LDS tables. Depth-1
// prefetch A/B loop (r6/r7 skeleton) with the 16-broadcast bf16-packed core.
__global__ __launch_bounds__(256) void tam_main(
    const float* __restrict__ regime,
    const int*   __restrict__ obs,
    const int*   __restrict__ rewards,
    const int*   __restrict__ dones_i,   // float32 0/1 read as int bits
    const int*   __restrict__ actions,
    const float* __restrict__ ws,
    float* __restrict__ out)
{
    __shared__ float4 sTF[2048];         // 32 KB fp32 transitions
    __shared__ float sE[L_N];            // 17.1 KB emission block
    const int tid  = threadIdx.x;
    const int lane = tid & 63;
    const int wid  = tid >> 6;
    const int sl   = lane & 31;
    const int b    = blockIdx.x * 4 + wid;

    // stage T (32 KB) and emissions (17.1 KB) into LDS — 256 threads
    {
        const uint4* gt = reinterpret_cast<const uint4*>(ws);
        uint4* st = reinterpret_cast<uint4*>(sTF);
        #pragma unroll
        for (int i = 0; i < 8; ++i) st[tid + i * 256] = gt[tid + i * 256];
        const float4* ge = reinterpret_cast<const float4*>(ws + OT_OFF);
        float4* s4 = reinterpret_cast<float4*>(sE);
        #pragma unroll 1
        for (int i = tid; i < L_N / 4; i += 256) s4[i] = ge[i];
    }
    __syncthreads();

    // per-lane packed step-pair indices: lane i holds steps 2i (low16), 2i+1 (high16)
    const int t0 = 2 * lane, t1 = 2 * lane + 1;
    const int o0 = obs[t0 * B_N + b],      o1 = obs[t1 * B_N + b];
    const int r0 = rewards[t0 * B_N + b],  r1 = rewards[t1 * B_N + b];
    const int a0 = actions[t0 * B_N + b],  a1 = actions[t1 * B_N + b];
    const int d0 = dones_i[t0 * B_N + b],  d1 = dones_i[t1 * B_N + b];
    const int vpk = (o0 | (r0 << 6) | (a0 << 9)) |
                    ((o1 | (r1 << 6) | (a1 << 9)) << 16);

    // first-done step t* via ballot (per-wave; no done checks in the hot loop)
    const unsigned long long mE = __ballot(d0 != 0);
    const unsigned long long mO = __ballot(d1 != 0);
    const int tE = mE ? 2 * __builtin_ctzll(mE)     : (1 << 30);
    const int tO = mO ? 2 * __builtin_ctzll(mO) + 1 : (1 << 30);
    const int tstar  = tE < tO ? tE : tO;
    const int nsteps = tstar < 128 ? tstar : 128;

    // regime==1 -> action term excluded every step: use RT table (a ignored)
    const bool skipA = (regime[b] == 1.0f);
    const int eBase = skipA ? L_RT : L_RA;
    const int eMulR = skipA ? 32 : 256;
    const int eMulA = skipA ? 0 : 32;

    float u = sE[L_PI + sl];
    int ksum = 0;
    float eA, eB;
    float4 tfA[8], tfB[8];

    unsigned pkc = (unsigned)RLI(vpk, 0);
    unsigned pkn = (unsigned)RLI(vpk, 1);
    LOADE(eA, pkc & 0xffffu);
    LOADTF(tfA, (int)((pkc >> 9) & 7u));

    const int npairs = nsteps >> 1;
    #pragma unroll 1
    for (int i = 0; i < npairs; ++i) {
        // prefetch step 2i+1 (B), compute step 2i (A)
        LOADE(eB, pkc >> 16);
        LOADTF(tfB, (int)((pkc >> 25) & 7u));
        STEP(eA, tfA);
        // prefetch step 2i+2 (next A), compute step 2i+1 (B)
        LOADE(eA, pkn & 0xffffu);
        LOADTF(tfA, (int)((pkn >> 9) & 7u));
        STEP(eB, tfB);
        // rotate packed indices (readlane lane wraps mod 64; overflow unused)
        pkc = pkn;
        pkn = (unsigned)RLI(vpk, i + 2);
        RESCALE();
    }

    if (nsteps & 1) {           // leftover even-index step (data already staged)
        STEP(eA, tfA);
    }

    // terminal contribution at e = min(t*, 128): OT*RT only (no action term)
    {
        const int e  = nsteps;
        const int oe = obs[e * B_N + b];
        const int re = rewards[e * B_N + b];
        const float eo = sE[L_OT + oe * 32 + sl];
        const float rt = sE[L_RT + re * 32 + sl];
        float t = u * eo * rt;
        t += __shfl_xor(t, 1, 32);
        t += __shfl_xor(t, 2, 32);
        t += __shfl_xor(t, 4, 32);
        t += __shfl_xor(t, 8, 32);
        t += __shfl_xor(t, 16, 32);
        const float result = (float)ksum * 0.69314718055994531f + __logf(t);
        if (lane == 0) out[b] = result;
    }
}

extern "C" void kernel_launch(void* const* d_in, const int* in_sizes, int n_in,
                              void* d_out, int out_size, void* d_ws, size_t ws_size,
                              hipStream_t stream) {
    (void)in_sizes; (void)n_in; (void)out_size; (void)ws_size;
    const float* regime      = (const float*)d_in[0];
    const int*   obs         = (const int*)d_in[1];
    const int*   rewards     = (const int*)d_in[2];
    const int*   dones_i     = (const int*)d_in[3];
    const int*   actions     = (const int*)d_in[4];
    const float* params_s    = (const float*)d_in[5];
    const float* params_s_sa = (const float*)d_in[6];
    const float* params_o_s  = (const float*)d_in[7];
    const float* params_r_s  = (const float*)d_in[8];
    const float* params_a_s  = (const float*)d_in[9];
    float* ws  = (float*)d_ws;
    float* out = (float*)d_out;

    tam_prep<<<2, 256, 0, stream>>>(params_s, params_s_sa, params_o_s,
                                    params_r_s, params_a_s, ws);
    tam_main<<<256, 256, 0, stream>>>(regime, obs, rewards, dones_i, actions, ws, out);
}